// Round 1
// baseline (102.903 us; speedup 1.0000x reference)
//
#include <hip/hip_runtime.h>

#define BSZ 16
#define SSZ 8192
#define FSZ 256
#define EPSV 1e-5f

// Kernel 1: ind[s] = (any batch has change point at s), ind[0] forced 0
__global__ void cp_reduce_kernel(const int* __restrict__ cp, int* __restrict__ ind) {
    int s = blockIdx.x * blockDim.x + threadIdx.x;
    if (s >= SSZ) return;
    int a = 0;
#pragma unroll
    for (int b = 0; b < BSZ; ++b) a |= cp[b * SSZ + s];
    ind[s] = (s == 0) ? 0 : (a != 0 ? 1 : 0);
}

// Kernel 2: single block, inclusive scan of ind -> seg_starts[], nseg
__global__ __launch_bounds__(1024) void scan_kernel(const int* __restrict__ ind,
                                                    int* __restrict__ seg_starts,
                                                    int* __restrict__ nseg_out) {
    __shared__ int lds[1024];
    int t = threadIdx.x;
    int vals[8];
    int tot = 0;
#pragma unroll
    for (int i = 0; i < 8; ++i) {
        int s = t * 8 + i;
        int v = ind[s];
        vals[i] = v;
        tot += v;
    }
    lds[t] = tot;
    __syncthreads();
    // Hillis-Steele inclusive scan over 1024 thread totals
    for (int off = 1; off < 1024; off <<= 1) {
        int a = lds[t];
        int b = (t >= off) ? lds[t - off] : 0;
        __syncthreads();
        lds[t] = a + b;
        __syncthreads();
    }
    int run = lds[t] - tot;  // exclusive prefix for this thread
#pragma unroll
    for (int i = 0; i < 8; ++i) {
        int s = t * 8 + i;
        if (vals[i]) {
            run += 1;
            seg_starts[run] = s;  // boundary position starts segment `run`
        }
    }
    if (t == 0) seg_starts[0] = 0;
    if (t == 1023) nseg_out[0] = lds[1023] + 1;
}

// Kernel 3: one workgroup (4 waves) per (seg, b) item; lane owns 4 f-columns.
__global__ __launch_bounds__(256) void segnorm_kernel(const float4* __restrict__ x4,
                                                      const float4* __restrict__ w4p,
                                                      const float4* __restrict__ b4p,
                                                      const int* __restrict__ seg_starts,
                                                      const int* __restrict__ nseg_p,
                                                      float4* __restrict__ out4) {
    __shared__ float4 p_sum[4][64];
    __shared__ float4 p_ssq[4][64];
    const int nseg = nseg_p[0];
    const int nitems = nseg * BSZ;
    const int lane = threadIdx.x & 63;
    const int wave = threadIdx.x >> 6;
    const float4 w = w4p[lane];
    const float4 bb = b4p[lane];

    for (int item = blockIdx.x; item < nitems; item += gridDim.x) {
        const int seg = item >> 4;  // BSZ == 16
        const int b = item & 15;
        const int start = seg_starts[seg];
        const int end = (seg + 1 < nseg) ? seg_starts[seg + 1] : SSZ;

        const float4* px = x4 + (size_t)b * SSZ * 64 + lane;

        float4 sum = make_float4(0.f, 0.f, 0.f, 0.f);
        float4 ssq = make_float4(0.f, 0.f, 0.f, 0.f);
        for (int s = start + wave; s < end; s += 4) {
            float4 v = px[(size_t)s * 64];
            sum.x += v.x; sum.y += v.y; sum.z += v.z; sum.w += v.w;
            ssq.x += v.x * v.x; ssq.y += v.y * v.y; ssq.z += v.z * v.z; ssq.w += v.w * v.w;
        }
        p_sum[wave][lane] = sum;
        p_ssq[wave][lane] = ssq;
        __syncthreads();

        float4 ts = make_float4(0.f, 0.f, 0.f, 0.f);
        float4 tq = make_float4(0.f, 0.f, 0.f, 0.f);
#pragma unroll
        for (int wv = 0; wv < 4; ++wv) {
            float4 a = p_sum[wv][lane];
            float4 q = p_ssq[wv][lane];
            ts.x += a.x; ts.y += a.y; ts.z += a.z; ts.w += a.w;
            tq.x += q.x; tq.y += q.y; tq.z += q.z; tq.w += q.w;
        }
        __syncthreads();  // all reads done before next item's stores

        const float cnt = (float)(end - start);
        const float rc = 1.0f / cnt;
        float4 mean, rstd;
        mean.x = ts.x * rc; mean.y = ts.y * rc; mean.z = ts.z * rc; mean.w = ts.w * rc;
        float vx = fmaxf(tq.x * rc - mean.x * mean.x, 0.f);
        float vy = fmaxf(tq.y * rc - mean.y * mean.y, 0.f);
        float vz = fmaxf(tq.z * rc - mean.z * mean.z, 0.f);
        float vw = fmaxf(tq.w * rc - mean.w * mean.w, 0.f);
        rstd.x = 1.0f / sqrtf(vx + EPSV);
        rstd.y = 1.0f / sqrtf(vy + EPSV);
        rstd.z = 1.0f / sqrtf(vz + EPSV);
        rstd.w = 1.0f / sqrtf(vw + EPSV);

        float4* po = out4 + (size_t)b * SSZ * 64 + lane;
        for (int s = start + wave; s < end; s += 4) {
            float4 v = px[(size_t)s * 64];
            float4 o;
            o.x = (v.x - mean.x) * rstd.x * w.x + bb.x;
            o.y = (v.y - mean.y) * rstd.y * w.y + bb.y;
            o.z = (v.z - mean.z) * rstd.z * w.z + bb.z;
            o.w = (v.w - mean.w) * rstd.w * w.w + bb.w;
            po[(size_t)s * 64] = o;
        }
    }
}

extern "C" void kernel_launch(void* const* d_in, const int* in_sizes, int n_in,
                              void* d_out, int out_size, void* d_ws, size_t ws_size,
                              hipStream_t stream) {
    const float* x = (const float*)d_in[0];
    const float* w = (const float*)d_in[1];
    const float* bias = (const float*)d_in[2];
    const int* cp = (const int*)d_in[3];

    int* wsi = (int*)d_ws;
    int* nseg = wsi;              // [1]
    int* seg_starts = wsi + 64;   // [SSZ]
    int* ind = wsi + 64 + SSZ;    // [SSZ]

    cp_reduce_kernel<<<(SSZ + 255) / 256, 256, 0, stream>>>(cp, ind);
    scan_kernel<<<1, 1024, 0, stream>>>(ind, seg_starts, nseg);
    segnorm_kernel<<<2048, 256, 0, stream>>>((const float4*)x, (const float4*)w,
                                             (const float4*)bias, seg_starts, nseg,
                                             (float4*)d_out);
}